// Round 3
// baseline (2920.398 us; speedup 1.0000x reference)
//
#include <hip/hip_runtime.h>
#include <hip/hip_bf16.h>
#include <math.h>

// Problem constants
#define NB 1024
#define NT 20
#define NC 512
#define NH 8
#define NL 8
#define MTOK (NB*NT)        // 20480 tokens

using bf16 = __hip_bfloat16;
typedef float f32x4 __attribute__((ext_vector_type(4)));
typedef short s16x8 __attribute__((ext_vector_type(8)));

static __device__ __forceinline__ float us2f(unsigned short u) {
    union { float f; unsigned int i; } c; c.i = ((unsigned int)u) << 16; return c.f;
}
static __device__ __forceinline__ unsigned short f2bfu(float x) {
    union { bf16 b; unsigned short u; } c; c.b = __float2bfloat16(x); return c.u;
}
static __device__ __forceinline__ bf16 f2bf(float x) { return __float2bfloat16(x); }

// ---- async global->LDS copy: 16B per lane, wave-uniform LDS base ----
static __device__ __forceinline__ void cp16(const bf16* g, bf16* lds_base, int lane) {
#if __has_builtin(__builtin_amdgcn_global_load_lds)
    __builtin_amdgcn_global_load_lds(
        (const __attribute__((address_space(1))) unsigned int*)g,
        (__attribute__((address_space(3))) unsigned int*)lds_base, 16, 0, 0);
#else
    ((int4*)lds_base)[lane] = *(const int4*)g;
#endif
}

// ---- encoder: h = x @ enc_w + enc_b + wpe[1:T+1] ----
__global__ __launch_bounds__(256) void enc_kernel(
    const float* __restrict__ x, const float* __restrict__ ew,
    const float* __restrict__ eb, const float* __restrict__ wpe,
    float* __restrict__ h) {
    int idx = blockIdx.x * 256 + threadIdx.x;       // token*128 + c4
    int token = idx >> 7, c4 = idx & 127;
    int t = token % NT;
    float x0 = x[(size_t)token * 2], x1 = x[(size_t)token * 2 + 1];
    const float4* w4 = (const float4*)ew;
    float4 w0 = w4[c4], w1 = w4[128 + c4];
    float4 b = ((const float4*)eb)[c4];
    float4 pe = ((const float4*)(wpe + (size_t)(t + 1) * NC))[c4];
    float4 o;
    o.x = x0 * w0.x + x1 * w1.x + b.x + pe.x;
    o.y = x0 * w0.y + x1 * w1.y + b.y + pe.y;
    o.z = x0 * w0.z + x1 * w1.z + b.z + pe.z;
    o.w = x0 * w0.w + x1 * w1.w + b.w + pe.w;
    ((float4*)h)[idx] = o;
}

// ---- weight convert+transpose: in [L][K][N] f32 -> out [L][N][K] bf16 ----
__global__ __launch_bounds__(256) void wconv_kernel(
    const float* __restrict__ in, bf16* __restrict__ out, int K, int N) {
    __shared__ float tile[32][33];
    int z = blockIdx.z;
    int k0 = blockIdx.x * 32, n0 = blockIdx.y * 32;
    int tx = threadIdx.x & 31, ty = threadIdx.x >> 5;   // ty in [0,8)
    const float* src = in + (size_t)z * K * N;
    bf16* dst = out + (size_t)z * K * N;
#pragma unroll
    for (int i = 0; i < 4; ++i)
        tile[ty + i * 8][tx] = src[(size_t)(k0 + ty + i * 8) * N + n0 + tx];
    __syncthreads();
#pragma unroll
    for (int i = 0; i < 4; ++i)
        dst[(size_t)(n0 + ty + i * 8) * K + k0 + tx] = f2bf(tile[tx][ty + i * 8]);
}

// ---- LayerNorm (fp32 in) -> bf16 out. One wave per token. ----
__global__ __launch_bounds__(256) void ln_kernel(
    const float* __restrict__ h, const float* __restrict__ w,
    const float* __restrict__ b, bf16* __restrict__ out) {
    int lane = threadIdx.x & 63, wave = threadIdx.x >> 6;
    int token = blockIdx.x * 4 + wave;
    const float4* row = (const float4*)(h + (size_t)token * NC);
    float4 v0 = row[lane], v1 = row[lane + 64];
    float s  = v0.x + v0.y + v0.z + v0.w + v1.x + v1.y + v1.z + v1.w;
    float sq = v0.x*v0.x + v0.y*v0.y + v0.z*v0.z + v0.w*v0.w
             + v1.x*v1.x + v1.y*v1.y + v1.z*v1.z + v1.w*v1.w;
#pragma unroll
    for (int off = 32; off; off >>= 1) {
        s  += __shfl_xor(s, off, 64);
        sq += __shfl_xor(sq, off, 64);
    }
    float mean = s * (1.0f / NC);
    float var = sq * (1.0f / NC) - mean * mean;
    float rstd = rsqrtf(var + 1e-5f);
    const float4* w4 = (const float4*)w;
    const float4* b4 = (const float4*)b;
    float4 wa = w4[lane], wb = w4[lane + 64];
    float4 ba = b4[lane], bb = b4[lane + 64];
    ushort4 o0, o1;
    o0.x = f2bfu((v0.x - mean) * rstd * wa.x + ba.x);
    o0.y = f2bfu((v0.y - mean) * rstd * wa.y + ba.y);
    o0.z = f2bfu((v0.z - mean) * rstd * wa.z + ba.z);
    o0.w = f2bfu((v0.w - mean) * rstd * wa.w + ba.w);
    o1.x = f2bfu((v1.x - mean) * rstd * wb.x + bb.x);
    o1.y = f2bfu((v1.y - mean) * rstd * wb.y + bb.y);
    o1.z = f2bfu((v1.z - mean) * rstd * wb.z + bb.z);
    o1.w = f2bfu((v1.w - mean) * rstd * wb.w + bb.w);
    *(ushort4*)(out + (size_t)token * NC + lane * 4) = o0;
    *(ushort4*)(out + (size_t)token * NC + 256 + lane * 4) = o1;
}

// ---- GEMM: C[M,N] = A[M,K](bf16) @ Wt[N,K]^T(bf16) + epilogue ----
// LDS layout: 16B chunks xor-swizzled (phys = logical ^ ((row>>1)&3)) so
// ds_read_b128 fragment reads are 2-way (free) instead of 8-way conflicted.
// MFMA operands are SWAPPED (mfma(b,a)): lane's 4 acc regs = 4 consecutive n
// -> ushort4/float4 epilogue stores.
// EPI 0: +bias -> bf16 out      (qkv)
// EPI 1: +bias, += into fp32 residual buffer (proj / fc2)
// EPI 2: +bias, tanh-GELU -> bf16 out  (fc1)
template <int EPI>
__global__ __launch_bounds__(256) void gemm(
    const bf16* __restrict__ A, const bf16* __restrict__ Wt,
    const float* __restrict__ bias, float* __restrict__ resid_out,
    bf16* __restrict__ outb, int N, int K) {
    __shared__ __align__(16) bf16 lA[128 * 32];
    __shared__ __align__(16) bf16 lB[128 * 32];
    const int tid = threadIdx.x;
    const int lane = tid & 63;
    const int wave = tid >> 6;
    const int wm = wave >> 1, wn = wave & 1;

    // XCD-aware swizzle: each XCD (flat%8) owns a contiguous m-tile chunk,
    // n varies fastest within it -> per-XCD working set (A-chunk + full B) ~ L2.
    const int flat = blockIdx.y * gridDim.x + blockIdx.x;
    const int per = (gridDim.x * gridDim.y) >> 3;
    const int nid = (flat & 7) * per + (flat >> 3);
    const int mt = nid / gridDim.x;
    const int nt = nid - mt * gridDim.x;
    const int m0 = mt * 128, n0 = nt * 128;

    f32x4 acc[4][4] = {};

    // staging: 512 chunks of 16B per tile; LDS slot c -> row c>>2, phys chunk c&3;
    // the GLOBAL chunk loaded there is logical = phys ^ ((row>>1)&3).
    const int c0 = tid, c1 = tid + 256;
    const int r0 = c0 >> 2, q0 = (((c0 & 3) ^ ((r0 >> 1) & 3)) * 8);
    const int r1 = c1 >> 2, q1 = (((c1 & 3) ^ ((r1 >> 1) & 3)) * 8);
    const bf16* Ab = A + (size_t)m0 * K;
    const bf16* Bb = Wt + (size_t)n0 * K;
    bf16* lA0 = lA + (wave * 64) * 8;
    bf16* lA1 = lA + (256 + wave * 64) * 8;
    bf16* lB0 = lB + (wave * 64) * 8;
    bf16* lB1 = lB + (256 + wave * 64) * 8;

    const int fm = lane & 15;            // m (or n) within 16-tile
    // fragment k-chunk after swizzle: phys = (lane>>4) ^ ((fm>>1)&3)  (lane-const)
    const int fk = (((lane >> 4) ^ ((fm >> 1) & 3)) * 8);

    for (int k0 = 0; k0 < K; k0 += 32) {
        __syncthreads();
        cp16(Ab + (size_t)r0 * K + k0 + q0, lA0, lane);
        cp16(Ab + (size_t)r1 * K + k0 + q1, lA1, lane);
        cp16(Bb + (size_t)r0 * K + k0 + q0, lB0, lane);
        cp16(Bb + (size_t)r1 * K + k0 + q1, lB1, lane);
        __syncthreads();

        s16x8 af[4], bfr[4];
#pragma unroll
        for (int mi = 0; mi < 4; ++mi)
            af[mi] = *(const s16x8*)&lA[(wm * 64 + mi * 16 + fm) * 32 + fk];
#pragma unroll
        for (int ni = 0; ni < 4; ++ni)
            bfr[ni] = *(const s16x8*)&lB[(wn * 64 + ni * 16 + fm) * 32 + fk];
#pragma unroll
        for (int mi = 0; mi < 4; ++mi)
#pragma unroll
            for (int ni = 0; ni < 4; ++ni)
                acc[mi][ni] = __builtin_amdgcn_mfma_f32_16x16x32_bf16(
                    bfr[ni], af[mi], acc[mi][ni], 0, 0, 0);   // swapped: D[n][m] block
    }

    // swapped C/D: lane holds m = ec (fixed), n = er*4 + {0..3}  (contiguous!)
    const int er = lane >> 4;
    const int ec = lane & 15;
    float4 bc[4];
#pragma unroll
    for (int ni = 0; ni < 4; ++ni)
        bc[ni] = *(const float4*)&bias[n0 + wn * 64 + ni * 16 + er * 4];
#pragma unroll
    for (int mi = 0; mi < 4; ++mi) {
        int row = m0 + wm * 64 + mi * 16 + ec;
#pragma unroll
        for (int ni = 0; ni < 4; ++ni) {
            int colb = n0 + wn * 64 + ni * 16 + er * 4;
            size_t idx = (size_t)row * N + colb;
            float v0 = acc[mi][ni][0] + bc[ni].x;
            float v1 = acc[mi][ni][1] + bc[ni].y;
            float v2 = acc[mi][ni][2] + bc[ni].z;
            float v3 = acc[mi][ni][3] + bc[ni].w;
            if (EPI == 0) {
                ushort4 o = { f2bfu(v0), f2bfu(v1), f2bfu(v2), f2bfu(v3) };
                *(ushort4*)&outb[idx] = o;
            } else if (EPI == 1) {
                float4 old = *(const float4*)&resid_out[idx];
                float4 nw = { old.x + v0, old.y + v1, old.z + v2, old.w + v3 };
                *(float4*)&resid_out[idx] = nw;
            } else {
                // tanh-GELU via sigmoid: 0.5v(1+tanh(u)) = v*sigmoid(2u)
                float g0 = v0 * __builtin_amdgcn_rcpf(1.0f + __expf(-1.5957691f * v0 * (1.0f + 0.044715f * v0 * v0)));
                float g1 = v1 * __builtin_amdgcn_rcpf(1.0f + __expf(-1.5957691f * v1 * (1.0f + 0.044715f * v1 * v1)));
                float g2 = v2 * __builtin_amdgcn_rcpf(1.0f + __expf(-1.5957691f * v2 * (1.0f + 0.044715f * v2 * v2)));
                float g3 = v3 * __builtin_amdgcn_rcpf(1.0f + __expf(-1.5957691f * v3 * (1.0f + 0.044715f * v3 * v3)));
                ushort4 o = { f2bfu(g0), f2bfu(g1), f2bfu(g2), f2bfu(g3) };
                *(ushort4*)&outb[idx] = o;
            }
        }
    }
}

// ---- attention: one wave per (batch, head). T=20, D=64. ----
// Parallel phases: (1) all 400 score pairs across lanes, (2) lane-per-row
// softmax (no cross-lane reductions), (3) PV with lane=d, P rows broadcast.
__global__ __launch_bounds__(64) void attn_kernel(
    const bf16* __restrict__ qkv, bf16* __restrict__ y) {
    __shared__ __align__(16) float qs[NT][68];   // row stride 68 -> 272B, 16B aligned
    __shared__ __align__(16) float ks[NT][68];
    __shared__ float vT[64][21];                 // v transposed: vT[d][t]
    __shared__ __align__(16) float P[NT][24];    // scores -> probs; stride 24 -> 96B aligned
    const int lane = threadIdx.x;
    const int b = blockIdx.x >> 3, hh = blockIdx.x & 7;
    const bf16* base = qkv + (size_t)b * NT * (3 * NC) + hh * 64;

    // load q,k,v (bf16 pairs for 4B loads); v goes in transposed
    for (int idx = lane; idx < NT * 32; idx += 64) {
        int t = idx >> 5, d2 = (idx & 31) * 2;
        const unsigned short* p;
        p = (const unsigned short*)(base + (size_t)t * (3 * NC) + d2);
        qs[t][d2] = us2f(p[0]); qs[t][d2 + 1] = us2f(p[1]);
        p = (const unsigned short*)(base + (size_t)t * (3 * NC) + NC + d2);
        ks[t][d2] = us2f(p[0]); ks[t][d2 + 1] = us2f(p[1]);
        p = (const unsigned short*)(base + (size_t)t * (3 * NC) + 2 * NC + d2);
        vT[d2][t] = us2f(p[0]); vT[d2 + 1][t] = us2f(p[1]);
    }
    __syncthreads();

    // phase 1: scores. 400 (i,j) pairs over 64 lanes, float4 dots of length 64.
    for (int pp = lane; pp < NT * NT; pp += 64) {
        int i = (int)(((unsigned)pp * 52429u) >> 20);   // pp / 20
        int j = pp - i * 20;
        const float4* qi = (const float4*)qs[i];
        const float4* kj = (const float4*)ks[j];
        float s = 0.0f;
#pragma unroll
        for (int d4 = 0; d4 < 16; ++d4) {
            float4 a = qi[d4], c = kj[d4];
            s += a.x * c.x + a.y * c.y + a.z * c.z + a.w * c.w;
        }
        P[i][j] = s * 0.125f;   // 1/sqrt(64)
    }
    __syncthreads();

    // phase 2: softmax — lane i owns row i, fully lane-local.
    if (lane < NT) {
        int i = lane;
        float m = -INFINITY;
        for (int j = 0; j <= i; ++j) m = fmaxf(m, P[i][j]);
        float sum = 0.0f;
        for (int j = 0; j <= i; ++j) { float e = __expf(P[i][j] - m); P[i][j] = e; sum += e; }
        float inv = 1.0f / sum;
        for (int j = 0; j <= i; ++j) P[i][j] *= inv;
        for (int j = i + 1; j < NT; ++j) P[i][j] = 0.0f;
    }
    __syncthreads();

    // phase 3: PV. lane = d; v column in regs; P rows via b128 broadcast.
    float vr[NT];
#pragma unroll
    for (int j = 0; j < NT; ++j) vr[j] = vT[lane][j];
    bf16* yb = y + (size_t)b * NT * NC + hh * 64;
#pragma unroll
    for (int i = 0; i < NT; ++i) {
        const float4* pr = (const float4*)P[i];
        float o = 0.0f;
#pragma unroll
        for (int j4 = 0; j4 < 5; ++j4) {
            float4 pv = pr[j4];
            o += pv.x * vr[j4 * 4] + pv.y * vr[j4 * 4 + 1]
               + pv.z * vr[j4 * 4 + 2] + pv.w * vr[j4 * 4 + 3];
        }
        yb[(size_t)i * NC + lane] = f2bf(o);
    }
}

// ---- final LN + predictor (C -> 2). One wave per token. ----
__global__ __launch_bounds__(256) void lnf_pred_kernel(
    const float* __restrict__ h, const float* __restrict__ w,
    const float* __restrict__ b, const float* __restrict__ pw,
    const float* __restrict__ pb, float* __restrict__ out) {
    int lane = threadIdx.x & 63, wave = threadIdx.x >> 6;
    int token = blockIdx.x * 4 + wave;
    const float4* row = (const float4*)(h + (size_t)token * NC);
    float4 v0 = row[lane], v1 = row[lane + 64];
    float s  = v0.x + v0.y + v0.z + v0.w + v1.x + v1.y + v1.z + v1.w;
    float sq = v0.x*v0.x + v0.y*v0.y + v0.z*v0.z + v0.w*v0.w
             + v1.x*v1.x + v1.y*v1.y + v1.z*v1.z + v1.w*v1.w;
#pragma unroll
    for (int off = 32; off; off >>= 1) {
        s  += __shfl_xor(s, off, 64);
        sq += __shfl_xor(sq, off, 64);
    }
    float mean = s * (1.0f / NC);
    float var = sq * (1.0f / NC) - mean * mean;
    float rstd = rsqrtf(var + 1e-5f);
    const float4* w4 = (const float4*)w;
    const float4* b4 = (const float4*)b;
    float4 wa = w4[lane], wb = w4[lane + 64];
    float4 ba = b4[lane], bb = b4[lane + 64];
    const float2* pw2 = (const float2*)pw;
    float a0 = 0.0f, a1 = 0.0f;
    int c = lane * 4;
    float f; float2 pv;
    f = (v0.x - mean) * rstd * wa.x + ba.x; pv = pw2[c + 0]; a0 += f * pv.x; a1 += f * pv.y;
    f = (v0.y - mean) * rstd * wa.y + ba.y; pv = pw2[c + 1]; a0 += f * pv.x; a1 += f * pv.y;
    f = (v0.z - mean) * rstd * wa.z + ba.z; pv = pw2[c + 2]; a0 += f * pv.x; a1 += f * pv.y;
    f = (v0.w - mean) * rstd * wa.w + ba.w; pv = pw2[c + 3]; a0 += f * pv.x; a1 += f * pv.y;
    c = 256 + lane * 4;
    f = (v1.x - mean) * rstd * wb.x + bb.x; pv = pw2[c + 0]; a0 += f * pv.x; a1 += f * pv.y;
    f = (v1.y - mean) * rstd * wb.y + bb.y; pv = pw2[c + 1]; a0 += f * pv.x; a1 += f * pv.y;
    f = (v1.z - mean) * rstd * wb.z + bb.z; pv = pw2[c + 2]; a0 += f * pv.x; a1 += f * pv.y;
    f = (v1.w - mean) * rstd * wb.w + bb.w; pv = pw2[c + 3]; a0 += f * pv.x; a1 += f * pv.y;
#pragma unroll
    for (int off = 32; off; off >>= 1) {
        a0 += __shfl_xor(a0, off, 64);
        a1 += __shfl_xor(a1, off, 64);
    }
    if (lane == 0) {
        out[(size_t)token * 2]     = a0 + pb[0];
        out[(size_t)token * 2 + 1] = a1 + pb[1];
    }
}

extern "C" void kernel_launch(void* const* d_in, const int* in_sizes, int n_in,
                              void* d_out, int out_size, void* d_ws, size_t ws_size,
                              hipStream_t stream) {
    (void)in_sizes; (void)n_in; (void)out_size; (void)ws_size;
    const float* x      = (const float*)d_in[0];
    const float* enc_w  = (const float*)d_in[1];
    const float* enc_b  = (const float*)d_in[2];
    const float* wpe    = (const float*)d_in[3];
    const float* ln1_w  = (const float*)d_in[4];
    const float* ln1_b  = (const float*)d_in[5];
    const float* attn_w = (const float*)d_in[6];
    const float* attn_b = (const float*)d_in[7];
    const float* proj_w = (const float*)d_in[8];
    const float* proj_b = (const float*)d_in[9];
    const float* ln2_w  = (const float*)d_in[10];
    const float* ln2_b  = (const float*)d_in[11];
    const float* fc1_w  = (const float*)d_in[12];
    const float* fc1_b  = (const float*)d_in[13];
    const float* fc2_w  = (const float*)d_in[14];
    const float* fc2_b  = (const float*)d_in[15];
    const float* lnf_w  = (const float*)d_in[16];
    const float* lnf_b  = (const float*)d_in[17];
    const float* pred_w = (const float*)d_in[18];
    const float* pred_b = (const float*)d_in[19];
    float* out = (float*)d_out;

    char* p = (char*)d_ws;
    float* h  = (float*)p;  p += (size_t)MTOK * NC * 4;        // fp32 residual stream
    bf16* xa  = (bf16*)p;   p += (size_t)MTOK * NC * 2;        // ln out / attn out
    bf16* big = (bf16*)p;   p += (size_t)MTOK * (4 * NC) * 2;  // qkv (3C) / mlp hidden (4C)
    bf16* aT  = (bf16*)p;   p += (size_t)NL * (3 * NC) * NC * 2;
    bf16* pT  = (bf16*)p;   p += (size_t)NL * NC * NC * 2;
    bf16* f1T = (bf16*)p;   p += (size_t)NL * (4 * NC) * NC * 2;
    bf16* f2T = (bf16*)p;   p += (size_t)NL * NC * (4 * NC) * 2;

    enc_kernel<<<MTOK * 128 / 256, 256, 0, stream>>>(x, enc_w, enc_b, wpe, h);
    wconv_kernel<<<dim3(16, 48, NL), 256, 0, stream>>>(attn_w, aT, NC, 3 * NC);
    wconv_kernel<<<dim3(16, 16, NL), 256, 0, stream>>>(proj_w, pT, NC, NC);
    wconv_kernel<<<dim3(16, 64, NL), 256, 0, stream>>>(fc1_w, f1T, NC, 4 * NC);
    wconv_kernel<<<dim3(64, 16, NL), 256, 0, stream>>>(fc2_w, f2T, 4 * NC, NC);

    for (int l = 0; l < NL; ++l) {
        ln_kernel<<<MTOK / 4, 256, 0, stream>>>(h, ln1_w + l * NC, ln1_b + l * NC, xa);
        gemm<0><<<dim3(12, 160), 256, 0, stream>>>(
            xa, aT + (size_t)l * 3 * NC * NC, attn_b + l * 3 * NC, nullptr, big, 3 * NC, NC);
        attn_kernel<<<NB * NH, 64, 0, stream>>>(big, xa);
        gemm<1><<<dim3(4, 160), 256, 0, stream>>>(
            xa, pT + (size_t)l * NC * NC, proj_b + l * NC, h, nullptr, NC, NC);
        ln_kernel<<<MTOK / 4, 256, 0, stream>>>(h, ln2_w + l * NC, ln2_b + l * NC, xa);
        gemm<2><<<dim3(16, 160), 256, 0, stream>>>(
            xa, f1T + (size_t)l * 4 * NC * NC, fc1_b + l * 4 * NC, nullptr, big, 4 * NC, NC);
        gemm<1><<<dim3(4, 160), 256, 0, stream>>>(
            big, f2T + (size_t)l * NC * 4 * NC, fc2_b + l * NC, h, nullptr, NC, 4 * NC);
    }
    lnf_pred_kernel<<<MTOK / 4, 256, 0, stream>>>(h, lnf_w, lnf_b, pred_w, pred_b, out);
}

// Round 4
// 2538.602 us; speedup vs baseline: 1.1504x; 1.1504x over previous
//
#include <hip/hip_runtime.h>
#include <hip/hip_bf16.h>
#include <math.h>

// Problem constants
#define NB 1024
#define NT 20
#define NC 512
#define NH 8
#define NL 8
#define MTOK (NB*NT)        // 20480 tokens

using bf16 = __hip_bfloat16;
typedef float f32x4 __attribute__((ext_vector_type(4)));
typedef short s16x8 __attribute__((ext_vector_type(8)));

static __device__ __forceinline__ float us2f(unsigned short u) {
    union { float f; unsigned int i; } c; c.i = ((unsigned int)u) << 16; return c.f;
}
static __device__ __forceinline__ unsigned short f2bfu(float x) {
    union { bf16 b; unsigned short u; } c; c.b = __float2bfloat16(x); return c.u;
}
static __device__ __forceinline__ bf16 f2bf(float x) { return __float2bfloat16(x); }

// ---- async global->LDS copy: 16B per lane, wave-uniform LDS base ----
static __device__ __forceinline__ void cp16(const bf16* g, bf16* lds_base, int lane) {
#if __has_builtin(__builtin_amdgcn_global_load_lds)
    __builtin_amdgcn_global_load_lds(
        (const __attribute__((address_space(1))) unsigned int*)g,
        (__attribute__((address_space(3))) unsigned int*)lds_base, 16, 0, 0);
#else
    ((int4*)lds_base)[lane] = *(const int4*)g;
#endif
}

static __device__ __forceinline__ void sync_sched() {
#if __has_builtin(__builtin_amdgcn_sched_barrier)
    __builtin_amdgcn_sched_barrier(0);
#endif
}

// tanh-GELU via sigmoid: 0.5v(1+tanh(u)) = v*sigmoid(2u)
static __device__ __forceinline__ float gelu_f(float v) {
    return v * __builtin_amdgcn_rcpf(
        1.0f + __expf(-1.5957691f * v * (1.0f + 0.044715f * v * v)));
}

// ---- encoder: h = x @ enc_w + enc_b + wpe[1:T+1] ----
__global__ __launch_bounds__(256) void enc_kernel(
    const float* __restrict__ x, const float* __restrict__ ew,
    const float* __restrict__ eb, const float* __restrict__ wpe,
    float* __restrict__ h) {
    int idx = blockIdx.x * 256 + threadIdx.x;       // token*128 + c4
    int token = idx >> 7, c4 = idx & 127;
    int t = token % NT;
    float x0 = x[(size_t)token * 2], x1 = x[(size_t)token * 2 + 1];
    const float4* w4 = (const float4*)ew;
    float4 w0 = w4[c4], w1 = w4[128 + c4];
    float4 b = ((const float4*)eb)[c4];
    float4 pe = ((const float4*)(wpe + (size_t)(t + 1) * NC))[c4];
    float4 o;
    o.x = x0 * w0.x + x1 * w1.x + b.x + pe.x;
    o.y = x0 * w0.y + x1 * w1.y + b.y + pe.y;
    o.z = x0 * w0.z + x1 * w1.z + b.z + pe.z;
    o.w = x0 * w0.w + x1 * w1.w + b.w + pe.w;
    ((float4*)h)[idx] = o;
}

// ---- weight convert+transpose: in [L][K][N] f32 -> out [L][N][K] bf16 ----
__global__ __launch_bounds__(256) void wconv_kernel(
    const float* __restrict__ in, bf16* __restrict__ out, int K, int N) {
    __shared__ float tile[32][33];
    int z = blockIdx.z;
    int k0 = blockIdx.x * 32, n0 = blockIdx.y * 32;
    int tx = threadIdx.x & 31, ty = threadIdx.x >> 5;   // ty in [0,8)
    const float* src = in + (size_t)z * K * N;
    bf16* dst = out + (size_t)z * K * N;
#pragma unroll
    for (int i = 0; i < 4; ++i)
        tile[ty + i * 8][tx] = src[(size_t)(k0 + ty + i * 8) * N + n0 + tx];
    __syncthreads();
#pragma unroll
    for (int i = 0; i < 4; ++i)
        dst[(size_t)(n0 + ty + i * 8) * K + k0 + tx] = f2bf(tile[tx][ty + i * 8]);
}

// ---- LayerNorm (fp32 in) -> bf16 out. One wave per token. ----
__global__ __launch_bounds__(256) void ln_kernel(
    const float* __restrict__ h, const float* __restrict__ w,
    const float* __restrict__ b, bf16* __restrict__ out) {
    int lane = threadIdx.x & 63, wave = threadIdx.x >> 6;
    int token = blockIdx.x * 4 + wave;
    const float4* row = (const float4*)(h + (size_t)token * NC);
    float4 v0 = row[lane], v1 = row[lane + 64];
    float s  = v0.x + v0.y + v0.z + v0.w + v1.x + v1.y + v1.z + v1.w;
    float sq = v0.x*v0.x + v0.y*v0.y + v0.z*v0.z + v0.w*v0.w
             + v1.x*v1.x + v1.y*v1.y + v1.z*v1.z + v1.w*v1.w;
#pragma unroll
    for (int off = 32; off; off >>= 1) {
        s  += __shfl_xor(s, off, 64);
        sq += __shfl_xor(sq, off, 64);
    }
    float mean = s * (1.0f / NC);
    float var = sq * (1.0f / NC) - mean * mean;
    float rstd = rsqrtf(var + 1e-5f);
    const float4* w4 = (const float4*)w;
    const float4* b4 = (const float4*)b;
    float4 wa = w4[lane], wb = w4[lane + 64];
    float4 ba = b4[lane], bb = b4[lane + 64];
    ushort4 o0, o1;
    o0.x = f2bfu((v0.x - mean) * rstd * wa.x + ba.x);
    o0.y = f2bfu((v0.y - mean) * rstd * wa.y + ba.y);
    o0.z = f2bfu((v0.z - mean) * rstd * wa.z + ba.z);
    o0.w = f2bfu((v0.w - mean) * rstd * wa.w + ba.w);
    o1.x = f2bfu((v1.x - mean) * rstd * wb.x + bb.x);
    o1.y = f2bfu((v1.y - mean) * rstd * wb.y + bb.y);
    o1.z = f2bfu((v1.z - mean) * rstd * wb.z + bb.z);
    o1.w = f2bfu((v1.w - mean) * rstd * wb.w + bb.w);
    *(ushort4*)(out + (size_t)token * NC + lane * 4) = o0;
    *(ushort4*)(out + (size_t)token * NC + 256 + lane * 4) = o1;
}

// ---- GEMM 128x128 tile: C = A[M,K] @ Wt[N,K]^T + epilogue ----
// XOR-swizzled LDS (conflict-free ds_read_b128), double-buffered staging with
// raw s_barrier + s_waitcnt vmcnt(4) so prefetch loads stay in flight.
// EPI 0: +bias -> bf16 | EPI 1: +bias += fp32 resid | EPI 2: +bias,GELU -> bf16
template <int EPI>
__global__ __launch_bounds__(256) void gemm(
    const bf16* __restrict__ A, const bf16* __restrict__ Wt,
    const float* __restrict__ bias, float* __restrict__ resid_out,
    bf16* __restrict__ outb, int N, int K) {
    __shared__ __align__(16) bf16 lA[2][128 * 32];
    __shared__ __align__(16) bf16 lB[2][128 * 32];
    const int tid = threadIdx.x;
    const int lane = tid & 63;
    const int wave = tid >> 6;
    const int wm = wave >> 1, wn = wave & 1;

    // XCD-aware swizzle: each XCD (flat%8) owns a contiguous m-chunk.
    const int flat = blockIdx.y * gridDim.x + blockIdx.x;
    const int per = (gridDim.x * gridDim.y) >> 3;
    const int nid = (flat & 7) * per + (flat >> 3);
    const int mt = nid / gridDim.x;
    const int nt = nid - mt * gridDim.x;
    const int m0 = mt * 128, n0 = nt * 128;

    f32x4 acc[4][4] = {};

    // staging: LDS slot c -> row c>>2, phys chunk c&3; global chunk = phys ^ ((row>>1)&3)
    const int c0 = tid, c1 = tid + 256;
    const int r0 = c0 >> 2, q0 = (((c0 & 3) ^ ((r0 >> 1) & 3)) * 8);
    const int r1 = c1 >> 2, q1 = (((c1 & 3) ^ ((r1 >> 1) & 3)) * 8);
    const bf16* Ab = A + (size_t)m0 * K;
    const bf16* Bb = Wt + (size_t)n0 * K;

    const int fm = lane & 15;
    const int fk = (((lane >> 4) ^ ((fm >> 1) & 3)) * 8);   // swizzled k-chunk
    const int iters = K / 32;

    auto stage = [&](int kk, int buf) {
        cp16(Ab + (size_t)r0 * K + kk + q0, &lA[buf][(wave * 64) * 8], lane);
        cp16(Ab + (size_t)r1 * K + kk + q1, &lA[buf][(256 + wave * 64) * 8], lane);
        cp16(Bb + (size_t)r0 * K + kk + q0, &lB[buf][(wave * 64) * 8], lane);
        cp16(Bb + (size_t)r1 * K + kk + q1, &lB[buf][(256 + wave * 64) * 8], lane);
    };
    stage(0, 0);
    for (int it = 0; it < iters; ++it) {
        const int cur = it & 1;
        const int kn = (it + 1 < iters) ? (it + 1) * 32 : 0;   // wrap: dummy reload
        __builtin_amdgcn_s_barrier();          // all done reading buf cur^1
        stage(kn, cur ^ 1);                    // prefetch next tile
        __builtin_amdgcn_s_waitcnt(0xF74);     // vmcnt(4): cur's loads complete
        __builtin_amdgcn_s_barrier();          // cur ready for everyone
        sync_sched();                          // no ds_read hoists above this

        s16x8 af[4], bfr[4];
#pragma unroll
        for (int mi = 0; mi < 4; ++mi)
            af[mi] = *(const s16x8*)&lA[cur][(wm * 64 + mi * 16 + fm) * 32 + fk];
#pragma unroll
        for (int ni = 0; ni < 4; ++ni)
            bfr[ni] = *(const s16x8*)&lB[cur][(wn * 64 + ni * 16 + fm) * 32 + fk];
#pragma unroll
        for (int mi = 0; mi < 4; ++mi)
#pragma unroll
            for (int ni = 0; ni < 4; ++ni)
                acc[mi][ni] = __builtin_amdgcn_mfma_f32_16x16x32_bf16(
                    af[mi], bfr[ni], acc[mi][ni], 0, 0, 0);
    }

    const int er = lane >> 4;   // C/D: row = er*4 + r, col = lane&15
    const int ec = lane & 15;
#pragma unroll
    for (int mi = 0; mi < 4; ++mi) {
#pragma unroll
        for (int ni = 0; ni < 4; ++ni) {
            int col = n0 + wn * 64 + ni * 16 + ec;
            float bcol = bias[col];
#pragma unroll
            for (int r = 0; r < 4; ++r) {
                int row = m0 + wm * 64 + mi * 16 + er * 4 + r;
                float v = acc[mi][ni][r] + bcol;
                size_t idx = (size_t)row * N + col;
                if (EPI == 0) {
                    outb[idx] = f2bf(v);
                } else if (EPI == 1) {
                    resid_out[idx] += v;
                } else {
                    outb[idx] = f2bf(gelu_f(v));
                }
            }
        }
    }
}

// ---- GEMM 128x64 tile (for N=512 gemms: 1280 blocks instead of 640) ----
// 4 waves stacked on m; wave tile 32x64. Same swizzle + dbuf pipeline.
template <int EPI>
__global__ __launch_bounds__(256) void gemm64(
    const bf16* __restrict__ A, const bf16* __restrict__ Wt,
    const float* __restrict__ bias, float* __restrict__ resid_out,
    bf16* __restrict__ outb, int N, int K) {
    __shared__ __align__(16) bf16 lA[2][128 * 32];
    __shared__ __align__(16) bf16 lB[2][64 * 32];
    const int tid = threadIdx.x;
    const int lane = tid & 63;
    const int wave = tid >> 6;

    const int flat = blockIdx.y * gridDim.x + blockIdx.x;
    const int per = (gridDim.x * gridDim.y) >> 3;
    const int nid = (flat & 7) * per + (flat >> 3);
    const int mt = nid / gridDim.x;
    const int nt = nid - mt * gridDim.x;
    const int m0 = mt * 128, n0 = nt * 64;

    f32x4 acc[2][4] = {};

    const int c0 = tid, c1 = tid + 256;
    const int r0 = c0 >> 2, q0 = (((c0 & 3) ^ ((r0 >> 1) & 3)) * 8);
    const int r1 = c1 >> 2, q1 = (((c1 & 3) ^ ((r1 >> 1) & 3)) * 8);
    const bf16* Ab = A + (size_t)m0 * K;
    const bf16* Bb = Wt + (size_t)n0 * K;

    const int fm = lane & 15;
    const int fk = (((lane >> 4) ^ ((fm >> 1) & 3)) * 8);
    const int iters = K / 32;

    auto stage = [&](int kk, int buf) {
        cp16(Ab + (size_t)r0 * K + kk + q0, &lA[buf][(wave * 64) * 8], lane);
        cp16(Ab + (size_t)r1 * K + kk + q1, &lA[buf][(256 + wave * 64) * 8], lane);
        cp16(Bb + (size_t)r0 * K + kk + q0, &lB[buf][(wave * 64) * 8], lane);
    };
    stage(0, 0);
    for (int it = 0; it < iters; ++it) {
        const int cur = it & 1;
        const int kn = (it + 1 < iters) ? (it + 1) * 32 : 0;
        __builtin_amdgcn_s_barrier();
        stage(kn, cur ^ 1);
        __builtin_amdgcn_s_waitcnt(0xF73);     // vmcnt(3)
        __builtin_amdgcn_s_barrier();
        sync_sched();

        s16x8 af[2], bfr[4];
#pragma unroll
        for (int mi = 0; mi < 2; ++mi)
            af[mi] = *(const s16x8*)&lA[cur][(wave * 32 + mi * 16 + fm) * 32 + fk];
#pragma unroll
        for (int ni = 0; ni < 4; ++ni)
            bfr[ni] = *(const s16x8*)&lB[cur][(ni * 16 + fm) * 32 + fk];
#pragma unroll
        for (int mi = 0; mi < 2; ++mi)
#pragma unroll
            for (int ni = 0; ni < 4; ++ni)
                acc[mi][ni] = __builtin_amdgcn_mfma_f32_16x16x32_bf16(
                    af[mi], bfr[ni], acc[mi][ni], 0, 0, 0);
    }

    const int er = lane >> 4;
    const int ec = lane & 15;
#pragma unroll
    for (int mi = 0; mi < 2; ++mi) {
#pragma unroll
        for (int ni = 0; ni < 4; ++ni) {
            int col = n0 + ni * 16 + ec;
            float bcol = bias[col];
#pragma unroll
            for (int r = 0; r < 4; ++r) {
                int row = m0 + wave * 32 + mi * 16 + er * 4 + r;
                float v = acc[mi][ni][r] + bcol;
                size_t idx = (size_t)row * N + col;
                if (EPI == 0) {
                    outb[idx] = f2bf(v);
                } else if (EPI == 1) {
                    resid_out[idx] += v;
                } else {
                    outb[idx] = f2bf(gelu_f(v));
                }
            }
        }
    }
}

// ---- attention: one wave per (batch, head). T=20, D=64. ----
__global__ __launch_bounds__(64) void attn_kernel(
    const bf16* __restrict__ qkv, bf16* __restrict__ y) {
    __shared__ __align__(16) float qs[NT][68];
    __shared__ __align__(16) float ks[NT][68];
    __shared__ float vT[64][21];
    __shared__ __align__(16) float P[NT][24];
    const int lane = threadIdx.x;
    const int b = blockIdx.x >> 3, hh = blockIdx.x & 7;
    const bf16* base = qkv + (size_t)b * NT * (3 * NC) + hh * 64;

    for (int idx = lane; idx < NT * 32; idx += 64) {
        int t = idx >> 5, d2 = (idx & 31) * 2;
        const unsigned short* p;
        p = (const unsigned short*)(base + (size_t)t * (3 * NC) + d2);
        qs[t][d2] = us2f(p[0]); qs[t][d2 + 1] = us2f(p[1]);
        p = (const unsigned short*)(base + (size_t)t * (3 * NC) + NC + d2);
        ks[t][d2] = us2f(p[0]); ks[t][d2 + 1] = us2f(p[1]);
        p = (const unsigned short*)(base + (size_t)t * (3 * NC) + 2 * NC + d2);
        vT[d2][t] = us2f(p[0]); vT[d2 + 1][t] = us2f(p[1]);
    }
    __syncthreads();

    for (int pp = lane; pp < NT * NT; pp += 64) {
        int i = (int)(((unsigned)pp * 52429u) >> 20);   // pp / 20
        int j = pp - i * 20;
        const float4* qi = (const float4*)qs[i];
        const float4* kj = (const float4*)ks[j];
        float s = 0.0f;
#pragma unroll
        for (int d4 = 0; d4 < 16; ++d4) {
            float4 a = qi[d4], c = kj[d4];
            s += a.x * c.x + a.y * c.y + a.z * c.z + a.w * c.w;
        }
        P[i][j] = s * 0.125f;
    }
    __syncthreads();

    if (lane < NT) {
        int i = lane;
        float m = -INFINITY;
        for (int j = 0; j <= i; ++j) m = fmaxf(m, P[i][j]);
        float sum = 0.0f;
        for (int j = 0; j <= i; ++j) { float e = __expf(P[i][j] - m); P[i][j] = e; sum += e; }
        float inv = 1.0f / sum;
        for (int j = 0; j <= i; ++j) P[i][j] *= inv;
        for (int j = i + 1; j < NT; ++j) P[i][j] = 0.0f;
    }
    __syncthreads();

    float vr[NT];
#pragma unroll
    for (int j = 0; j < NT; ++j) vr[j] = vT[lane][j];
    bf16* yb = y + (size_t)b * NT * NC + hh * 64;
#pragma unroll
    for (int i = 0; i < NT; ++i) {
        const float4* pr = (const float4*)P[i];
        float o = 0.0f;
#pragma unroll
        for (int j4 = 0; j4 < 5; ++j4) {
            float4 pv = pr[j4];
            o += pv.x * vr[j4 * 4] + pv.y * vr[j4 * 4 + 1]
               + pv.z * vr[j4 * 4 + 2] + pv.w * vr[j4 * 4 + 3];
        }
        yb[(size_t)i * NC + lane] = f2bf(o);
    }
}

// ---- final LN + predictor (C -> 2). One wave per token. ----
__global__ __launch_bounds__(256) void lnf_pred_kernel(
    const float* __restrict__ h, const float* __restrict__ w,
    const float* __restrict__ b, const float* __restrict__ pw,
    const float* __restrict__ pb, float* __restrict__ out) {
    int lane = threadIdx.x & 63, wave = threadIdx.x >> 6;
    int token = blockIdx.x * 4 + wave;
    const float4* row = (const float4*)(h + (size_t)token * NC);
    float4 v0 = row[lane], v1 = row[lane + 64];
    float s  = v0.x + v0.y + v0.z + v0.w + v1.x + v1.y + v1.z + v1.w;
    float sq = v0.x*v0.x + v0.y*v0.y + v0.z*v0.z + v0.w*v0.w
             + v1.x*v1.x + v1.y*v1.y + v1.z*v1.z + v1.w*v1.w;
#pragma unroll
    for (int off = 32; off; off >>= 1) {
        s  += __shfl_xor(s, off, 64);
        sq += __shfl_xor(sq, off, 64);
    }
    float mean = s * (1.0f / NC);
    float var = sq * (1.0f / NC) - mean * mean;
    float rstd = rsqrtf(var + 1e-5f);
    const float4* w4 = (const float4*)w;
    const float4* b4 = (const float4*)b;
    float4 wa = w4[lane], wb = w4[lane + 64];
    float4 ba = b4[lane], bb = b4[lane + 64];
    const float2* pw2 = (const float2*)pw;
    float a0 = 0.0f, a1 = 0.0f;
    int c = lane * 4;
    float f; float2 pv;
    f = (v0.x - mean) * rstd * wa.x + ba.x; pv = pw2[c + 0]; a0 += f * pv.x; a1 += f * pv.y;
    f = (v0.y - mean) * rstd * wa.y + ba.y; pv = pw2[c + 1]; a0 += f * pv.x; a1 += f * pv.y;
    f = (v0.z - mean) * rstd * wa.z + ba.z; pv = pw2[c + 2]; a0 += f * pv.x; a1 += f * pv.y;
    f = (v0.w - mean) * rstd * wa.w + ba.w; pv = pw2[c + 3]; a0 += f * pv.x; a1 += f * pv.y;
    c = 256 + lane * 4;
    f = (v1.x - mean) * rstd * wb.x + bb.x; pv = pw2[c + 0]; a0 += f * pv.x; a1 += f * pv.y;
    f = (v1.y - mean) * rstd * wb.y + bb.y; pv = pw2[c + 1]; a0 += f * pv.x; a1 += f * pv.y;
    f = (v1.z - mean) * rstd * wb.z + bb.z; pv = pw2[c + 2]; a0 += f * pv.x; a1 += f * pv.y;
    f = (v1.w - mean) * rstd * wb.w + bb.w; pv = pw2[c + 3]; a0 += f * pv.x; a1 += f * pv.y;
#pragma unroll
    for (int off = 32; off; off >>= 1) {
        a0 += __shfl_xor(a0, off, 64);
        a1 += __shfl_xor(a1, off, 64);
    }
    if (lane == 0) {
        out[(size_t)token * 2]     = a0 + pb[0];
        out[(size_t)token * 2 + 1] = a1 + pb[1];
    }
}

extern "C" void kernel_launch(void* const* d_in, const int* in_sizes, int n_in,
                              void* d_out, int out_size, void* d_ws, size_t ws_size,
                              hipStream_t stream) {
    (void)in_sizes; (void)n_in; (void)out_size; (void)ws_size;
    const float* x      = (const float*)d_in[0];
    const float* enc_w  = (const float*)d_in[1];
    const float* enc_b  = (const float*)d_in[2];
    const float* wpe    = (const float*)d_in[3];
    const float* ln1_w  = (const float*)d_in[4];
    const float* ln1_b  = (const float*)d_in[5];
    const float* attn_w = (const float*)d_in[6];
    const float* attn_b = (const float*)d_in[7];
    const float* proj_w = (const float*)d_in[8];
    const float* proj_b = (const float*)d_in[9];
    const float* ln2_w  = (const float*)d_in[10];
    const float* ln2_b  = (const float*)d_in[11];
    const float* fc1_w  = (const float*)d_in[12];
    const float* fc1_b  = (const float*)d_in[13];
    const float* fc2_w  = (const float*)d_in[14];
    const float* fc2_b  = (const float*)d_in[15];
    const float* lnf_w  = (const float*)d_in[16];
    const float* lnf_b  = (const float*)d_in[17];
    const float* pred_w = (const float*)d_in[18];
    const float* pred_b = (const float*)d_in[19];
    float* out = (float*)d_out;

    char* p = (char*)d_ws;
    float* h  = (float*)p;  p += (size_t)MTOK * NC * 4;        // fp32 residual stream
    bf16* xa  = (bf16*)p;   p += (size_t)MTOK * NC * 2;        // ln out / attn out
    bf16* big = (bf16*)p;   p += (size_t)MTOK * (4 * NC) * 2;  // qkv (3C) / mlp hidden (4C)
    bf16* aT  = (bf16*)p;   p += (size_t)NL * (3 * NC) * NC * 2;
    bf16* pT  = (bf16*)p;   p += (size_t)NL * NC * NC * 2;
    bf16* f1T = (bf16*)p;   p += (size_t)NL * (4 * NC) * NC * 2;
    bf16* f2T = (bf16*)p;   p += (size_t)NL * NC * (4 * NC) * 2;

    enc_kernel<<<MTOK * 128 / 256, 256, 0, stream>>>(x, enc_w, enc_b, wpe, h);
    wconv_kernel<<<dim3(16, 48, NL), 256, 0, stream>>>(attn_w, aT, NC, 3 * NC);
    wconv_kernel<<<dim3(16, 16, NL), 256, 0, stream>>>(proj_w, pT, NC, NC);
    wconv_kernel<<<dim3(16, 64, NL), 256, 0, stream>>>(fc1_w, f1T, NC, 4 * NC);
    wconv_kernel<<<dim3(64, 16, NL), 256, 0, stream>>>(fc2_w, f2T, 4 * NC, NC);

    for (int l = 0; l < NL; ++l) {
        ln_kernel<<<MTOK / 4, 256, 0, stream>>>(h, ln1_w + l * NC, ln1_b + l * NC, xa);
        gemm<0><<<dim3(12, 160), 256, 0, stream>>>(
            xa, aT + (size_t)l * 3 * NC * NC, attn_b + l * 3 * NC, nullptr, big, 3 * NC, NC);
        attn_kernel<<<NB * NH, 64, 0, stream>>>(big, xa);
        gemm64<1><<<dim3(8, 160), 256, 0, stream>>>(
            xa, pT + (size_t)l * NC * NC, proj_b + l * NC, h, nullptr, NC, NC);
        ln_kernel<<<MTOK / 4, 256, 0, stream>>>(h, ln2_w + l * NC, ln2_b + l * NC, xa);
        gemm<2><<<dim3(16, 160), 256, 0, stream>>>(
            xa, f1T + (size_t)l * 4 * NC * NC, fc1_b + l * 4 * NC, nullptr, big, 4 * NC, NC);
        gemm64<1><<<dim3(8, 160), 256, 0, stream>>>(
            big, f2T + (size_t)l * NC * 4 * NC, fc2_b + l * NC, h, nullptr, NC, 4 * NC);
    }
    lnf_pred_kernel<<<MTOK / 4, 256, 0, stream>>>(h, lnf_w, lnf_b, pred_w, pred_b, out);
}